// Round 2
// baseline (27143.439 us; speedup 1.0000x reference)
//
#include <hip/hip_runtime.h>
#include <hip/hip_bf16.h>
#include <cstddef>

using bf16x8 = __attribute__((ext_vector_type(8))) short;
using f32x4  = __attribute__((ext_vector_type(4))) float;

constexpr int Bb = 128;
constexpr int Tt = 256;
constexpr int Hh = 1024;
constexpr int Oo = 64;
constexpr int NBLK = 49;

__device__ __forceinline__ float bf2f(short s) {
  unsigned int u = ((unsigned int)(unsigned short)s) << 16;
  float f;
  __builtin_memcpy(&f, &u, 4);
  return f;
}
__device__ __forceinline__ short f2bf(float f) {
  unsigned int u;
  __builtin_memcpy(&u, &f, 4);
  u += 0x7fffu + ((u >> 16) & 1u);  // round-to-nearest-even
  return (short)(u >> 16);
}

// Monotonic grid barrier: all NBLK blocks co-resident (49 blocks, 256 thr,
// 36KB LDS -> >=1 block/CU on 256 CUs). Thread 0 does agent-scope acq_rel
// add + acquire spin; __syncthreads brackets give block-wide ordering.
// Same scheme as ROCm's cg::grid_group::sync, minus the cooperative API.
__device__ __forceinline__ void grid_barrier(unsigned int* bar, unsigned int target) {
  __syncthreads();
  if (threadIdx.x == 0) {
    __hip_atomic_fetch_add(bar, 1u, __ATOMIC_ACQ_REL, __HIP_MEMORY_SCOPE_AGENT);
    while (__hip_atomic_load(bar, __ATOMIC_ACQUIRE, __HIP_MEMORY_SCOPE_AGENT) < target) {
      __builtin_amdgcn_s_sleep(2);
    }
  }
  __syncthreads();
}

// ---------------------------------------------------------------------------
// Tiled GEMM: C[128 x 64] = A[128 x 1024](bf16) * B^T, B row j is W[j][k]
// (both operands K-contiguous). Block = 256 thr = 4 waves, wave = [64 x 32].
// A staged via double-buffered LDS (pad +8 -> only 2-way bank aliasing, free).
// B loaded direct from global (L2/LLC-resident weights) with 1-iter prefetch.
// One __syncthreads per K-chunk (double buffering removes the WAR barrier).
// ---------------------------------------------------------------------------
__device__ __forceinline__ void gemm_tile(
    const short* __restrict__ A, const short* __restrict__ Bw,
    int bstride, int colbase, short* __restrict__ As, f32x4 (&acc)[4][2]) {
  const int tid  = threadIdx.x;
  const int lane = tid & 63;
  const int wv   = tid >> 6;
  const int mbase = (wv >> 1) * 64;
  const int nbf   = colbase + (wv & 1) * 32;
  const int lm = lane & 15;
  const int q  = lane >> 4;

  const f32x4 z4 = {0.f, 0.f, 0.f, 0.f};
#pragma unroll
  for (int mt = 0; mt < 4; ++mt) { acc[mt][0] = z4; acc[mt][1] = z4; }

  // staging: thread -> one int4 (8 bf16) per 32-row slab, 4 slabs
  const int sr = tid >> 3;        // 0..31
  const int sc = (tid & 7) * 8;   // 0..56
  const short* Ag = A + sr * Hh + sc;

  int4 areg[4];
#pragma unroll
  for (int p = 0; p < 4; ++p) areg[p] = *(const int4*)(Ag + p * 32 * Hh);

  const short* b0p = Bw + (size_t)(nbf + lm) * bstride + q * 8;
  const short* b1p = Bw + (size_t)(nbf + 16 + lm) * bstride + q * 8;
  bf16x8 bfrag[2][2];
#pragma unroll
  for (int kc = 0; kc < 2; ++kc) {
    bfrag[kc][0] = *(const bf16x8*)(b0p + kc * 32);
    bfrag[kc][1] = *(const bf16x8*)(b1p + kc * 32);
  }

  for (int i = 0; i < 16; ++i) {
    short* Asc = As + (i & 1) * (128 * 72);
#pragma unroll
    for (int p = 0; p < 4; ++p)
      *(int4*)(Asc + (p * 32 + sr) * 72 + sc) = areg[p];
    const int kn = ((i + 1) & 15) * 64;  // wraps at tail; harmless in-bounds load
#pragma unroll
    for (int p = 0; p < 4; ++p)
      areg[p] = *(const int4*)(Ag + kn + p * 32 * Hh);
    bf16x8 bnext[2][2];
#pragma unroll
    for (int kc = 0; kc < 2; ++kc) {
      bnext[kc][0] = *(const bf16x8*)(b0p + kn + kc * 32);
      bnext[kc][1] = *(const bf16x8*)(b1p + kn + kc * 32);
    }
    __syncthreads();
    const short* Ar = Asc + mbase * 72 + q * 8;
#pragma unroll
    for (int kc = 0; kc < 2; ++kc) {
#pragma unroll
      for (int mt = 0; mt < 4; ++mt) {
        bf16x8 a = *(const bf16x8*)(Ar + (mt * 16 + lm) * 72 + kc * 32);
        acc[mt][0] = __builtin_amdgcn_mfma_f32_16x16x32_bf16(a, bfrag[kc][0], acc[mt][0], 0, 0, 0);
        acc[mt][1] = __builtin_amdgcn_mfma_f32_16x16x32_bf16(a, bfrag[kc][1], acc[mt][1], 0, 0, 0);
      }
    }
#pragma unroll
    for (int kc = 0; kc < 2; ++kc) {
      bfrag[kc][0] = bnext[kc][0];
      bfrag[kc][1] = bnext[kc][1];
    }
  }
}

// C/D fragment layout (verified, m89/m91): col = lane&15, row = (lane>>4)*4 + reg
#define EPILOGUE(CB, ...) do {                                             \
    const int nbf = (CB) + (wv & 1) * 32;                                  \
    _Pragma("unroll")                                                      \
    for (int mt = 0; mt < 4; ++mt) {                                       \
      _Pragma("unroll")                                                    \
      for (int nt = 0; nt < 2; ++nt) {                                     \
        _Pragma("unroll")                                                  \
        for (int r = 0; r < 4; ++r) {                                      \
          const int brow = mbase + mt * 16 + q * 4 + r;                    \
          const int col  = nbf + nt * 16 + lm;                             \
          const float z  = acc[mt][nt][r];                                 \
          __VA_ARGS__;                                                     \
        } } } } while (0)

struct RP {
  short* h1a; short* h1b; short* h2bf;
  float* h2f; float* uf; float* ug1f; float* acc2f; float* o1f;
  const short* prex;
  const short* whh1; const short* wih2; const short* whh2;
  const short* wg; const short* wo1; const short* wo2;
  const float* b_ih2; const float* b_hh2;
  const float* bg; const float* bo1; const float* bo2;
  float* out;
  unsigned int* bar;
};

// Phase A blocks: 0-15 h1-GEMM | 16-31 acc2=h2@Whh2 | 32-47 u-gate | 48 out(t-1)
// Phase B blocks: 0-15 h2 blend | 16-31 ug1=h1@Wg1   | 32 o1 head  | rest idle
__global__ void __launch_bounds__(256) rnn_kernel(RP p) {
  __shared__ short As[2 * 128 * 72];
  const int bid = blockIdx.x;
  const int tid = threadIdx.x;
  const int lane = tid & 63;
  const int wv = tid >> 6;
  const int mbase = (wv >> 1) * 64;
  const int lm = lane & 15;
  const int q = lane >> 4;
  f32x4 acc[4][2];
  unsigned int gen = 0;

  for (int t = 0; t < Tt; ++t) {
    const short* h1in  = (t & 1) ? p.h1b : p.h1a;  // h1(t-1)
    short*       h1out = (t & 1) ? p.h1a : p.h1b;  // h1(t)
    // ---------------- Phase A ----------------
    if (bid < 16) {
      const int cb = bid * 64;
      gemm_tile(h1in, p.whh1, Hh, cb, As, acc);
      EPILOGUE(cb, {
        const float v = z + bf2f(p.prex[((size_t)t * Bb + brow) * Hh + col]);
        h1out[brow * Hh + col] = f2bf(tanhf(v));
      });
    } else if (bid < 32) {
      const int cb = (bid - 16) * 64;
      gemm_tile(p.h2bf, p.whh2, Hh, cb, As, acc);
      EPILOGUE(cb, {
        p.acc2f[brow * Hh + col] = z + p.b_ih2[col] + p.b_hh2[col];
      });
    } else if (bid < 48) {
      if (t > 0) {
        const int cb = (bid - 32) * 64;
        gemm_tile(p.h2bf, p.wg + Hh, 2 * Hh, cb, As, acc);
        EPILOGUE(cb, {
          const int idx = brow * Hh + col;
          const float s = z + p.ug1f[idx] + p.bg[col];
          p.uf[idx] = 1.0f / (1.0f + expf(-s));
        });
      }
    } else {
      if (t > 0) {
        gemm_tile(p.h2bf, p.wo2, Hh, 0, As, acc);
        EPILOGUE(0, {
          p.out[(size_t)brow * (Tt * Oo) + (size_t)(t - 1) * Oo + col] =
              p.o1f[brow * Oo + col] + tanhf(z + p.bo2[col]);
        });
      }
    }
    gen += NBLK;
    grid_barrier(p.bar, gen);
    // ---------------- Phase B ----------------
    if (bid < 16) {
      const int cb = bid * 64;
      gemm_tile(h1out, p.wih2, Hh, cb, As, acc);
      EPILOGUE(cb, {
        const int idx = brow * Hh + col;
        const float hn  = tanhf(z + p.acc2f[idx]);
        const float u   = p.uf[idx];
        const float h2o = p.h2f[idx];
        const float nv  = fmaf(u, hn - h2o, h2o);  // u*hn + (1-u)*h2o
        p.h2f[idx]  = nv;
        p.h2bf[idx] = f2bf(nv);
      });
    } else if (bid < 32) {
      const int cb = (bid - 16) * 64;
      gemm_tile(h1out, p.wg, 2 * Hh, cb, As, acc);
      EPILOGUE(cb, { p.ug1f[brow * Hh + col] = z; });
    } else if (bid == 32) {
      gemm_tile(h1out, p.wo1, Hh, 0, As, acc);
      EPILOGUE(0, { p.o1f[brow * Oo + col] = tanhf(z + p.bo1[col]); });
    }
    gen += NBLK;
    grid_barrier(p.bar, gen);
  }
  // final output row t = T-1
  if (bid == 48) {
    gemm_tile(p.h2bf, p.wo2, Hh, 0, As, acc);
    EPILOGUE(0, {
      p.out[(size_t)brow * (Tt * Oo) + (size_t)(Tt - 1) * Oo + col] =
          p.o1f[brow * Oo + col] + tanhf(z + p.bo2[col]);
    });
  }
}

// pre_x[t][b][j] = x[b,t,:] @ W_ih1[j,:] + b_ih1[j] + b_hh1[j]  (stored bf16)
__global__ void __launch_bounds__(256) prex_kernel(
    const float* __restrict__ x, const float* __restrict__ wih1,
    const float* __restrict__ b_ih1, const float* __restrict__ b_hh1,
    short* __restrict__ prex) {
  const int tid = threadIdx.x;
  const int lane = tid & 63;
  const int wv = tid >> 6;
  const int lm = lane & 15;
  const int q = lane >> 4;
  const int bm = blockIdx.x >> 4;   // 512 row tiles of 64
  const int bn = blockIdx.x & 15;   // 16 col tiles of 64
  const int rowbase = bm * 64;
  const int col = bn * 64 + wv * 16 + lm;

  const f32x4 z4 = {0.f, 0.f, 0.f, 0.f};
  f32x4 acc[4];
#pragma unroll
  for (int mt = 0; mt < 4; ++mt) acc[mt] = z4;

#pragma unroll
  for (int kc = 0; kc < 2; ++kc) {
    const float* bp = wih1 + col * 64 + kc * 32 + q * 8;
    bf16x8 bf;
#pragma unroll
    for (int j = 0; j < 8; ++j) bf[j] = f2bf(bp[j]);
#pragma unroll
    for (int mt = 0; mt < 4; ++mt) {
      const float* ap = x + (size_t)(rowbase + mt * 16 + lm) * 64 + kc * 32 + q * 8;
      bf16x8 af;
#pragma unroll
      for (int j = 0; j < 8; ++j) af[j] = f2bf(ap[j]);
      acc[mt] = __builtin_amdgcn_mfma_f32_16x16x32_bf16(af, bf, acc[mt], 0, 0, 0);
    }
  }
  const float bia = b_ih1[col] + b_hh1[col];
#pragma unroll
  for (int mt = 0; mt < 4; ++mt) {
#pragma unroll
    for (int r = 0; r < 4; ++r) {
      const int row = rowbase + mt * 16 + q * 4 + r;  // row = b*256 + t
      const int b  = row >> 8;
      const int tt = row & 255;
      prex[((size_t)tt * Bb + b) * Hh + col] = f2bf(acc[mt][r] + bia);
    }
  }
}

__global__ void conv_kernel(const float* __restrict__ s, short* __restrict__ d, int n) {
  int i = blockIdx.x * blockDim.x + threadIdx.x;
  const int stride = gridDim.x * blockDim.x;
  for (; i < n; i += stride) d[i] = f2bf(s[i]);
}

__global__ void init_kernel(short* h1a, short* h1b, short* h2bf, float* h2f,
                            float* uf, unsigned int* bar) {
  const int i = blockIdx.x * blockDim.x + threadIdx.x;  // exactly 128*1024
  h1a[i] = 0; h1b[i] = 0; h2bf[i] = 0; h2f[i] = 0.f; uf[i] = 1.0f;
  if (i == 0) *bar = 0u;
}

extern "C" void kernel_launch(void* const* d_in, const int* in_sizes, int n_in,
                              void* d_out, int out_size, void* d_ws, size_t ws_size,
                              hipStream_t stream) {
  (void)in_sizes; (void)n_in; (void)out_size; (void)ws_size;
  const float* x      = (const float*)d_in[0];
  const float* W_ih1  = (const float*)d_in[1];
  const float* b_ih1  = (const float*)d_in[2];
  const float* W_hh1  = (const float*)d_in[3];
  const float* b_hh1  = (const float*)d_in[4];
  const float* W_ih2  = (const float*)d_in[5];
  const float* b_ih2  = (const float*)d_in[6];
  const float* W_hh2  = (const float*)d_in[7];
  const float* b_hh2  = (const float*)d_in[8];
  const float* Wg     = (const float*)d_in[9];
  const float* bg     = (const float*)d_in[10];
  const float* Wo1    = (const float*)d_in[11];
  const float* bo1    = (const float*)d_in[12];
  const float* Wo2    = (const float*)d_in[13];
  const float* bo2    = (const float*)d_in[14];

  char* ws = (char*)d_ws;
  size_t off = 0;
  auto alloc = [&](size_t bytes) -> void* {
    void* ptr = ws + off;
    off += (bytes + 255) & ~(size_t)255;
    return ptr;
  };
  short* whh1 = (short*)alloc((size_t)Hh * Hh * 2);
  short* wih2 = (short*)alloc((size_t)Hh * Hh * 2);
  short* whh2 = (short*)alloc((size_t)Hh * Hh * 2);
  short* wg   = (short*)alloc((size_t)Hh * 2 * Hh * 2);
  short* wo1  = (short*)alloc((size_t)Oo * Hh * 2);
  short* wo2  = (short*)alloc((size_t)Oo * Hh * 2);
  short* prex = (short*)alloc((size_t)Bb * Tt * Hh * 2);   // 67 MB
  short* h1a  = (short*)alloc((size_t)Bb * Hh * 2);
  short* h1b  = (short*)alloc((size_t)Bb * Hh * 2);
  short* h2bf = (short*)alloc((size_t)Bb * Hh * 2);
  float* h2f  = (float*)alloc((size_t)Bb * Hh * 4);
  float* uf   = (float*)alloc((size_t)Bb * Hh * 4);
  float* ug1f = (float*)alloc((size_t)Bb * Hh * 4);
  float* acc2f= (float*)alloc((size_t)Bb * Hh * 4);
  float* o1f  = (float*)alloc((size_t)Bb * Oo * 4);
  unsigned int* bar = (unsigned int*)alloc(256);

  conv_kernel<<<1024, 256, 0, stream>>>(W_hh1, whh1, Hh * Hh);
  conv_kernel<<<1024, 256, 0, stream>>>(W_ih2, wih2, Hh * Hh);
  conv_kernel<<<1024, 256, 0, stream>>>(W_hh2, whh2, Hh * Hh);
  conv_kernel<<<2048, 256, 0, stream>>>(Wg,    wg,   Hh * 2 * Hh);
  conv_kernel<<<256,  256, 0, stream>>>(Wo1,   wo1,  Oo * Hh);
  conv_kernel<<<256,  256, 0, stream>>>(Wo2,   wo2,  Oo * Hh);
  init_kernel<<<512, 256, 0, stream>>>(h1a, h1b, h2bf, h2f, uf, bar);
  prex_kernel<<<8192, 256, 0, stream>>>(x, W_ih1, b_ih1, b_hh1, prex);

  RP p;
  p.h1a = h1a; p.h1b = h1b; p.h2bf = h2bf;
  p.h2f = h2f; p.uf = uf; p.ug1f = ug1f; p.acc2f = acc2f; p.o1f = o1f;
  p.prex = prex;
  p.whh1 = whh1; p.wih2 = wih2; p.whh2 = whh2;
  p.wg = wg; p.wo1 = wo1; p.wo2 = wo2;
  p.b_ih2 = b_ih2; p.b_hh2 = b_hh2;
  p.bg = bg; p.bo1 = bo1; p.bo2 = bo2;
  p.out = (float*)d_out;
  p.bar = bar;

  rnn_kernel<<<NBLK, 256, 0, stream>>>(p);
}